// Round 5
// baseline (2285.818 us; speedup 1.0000x reference)
//
#include <hip/hip_runtime.h>

#define NUM_USERS 100000
#define NUM_ITEMS 50000
#define N_NODES   150000   // NUM_USERS + NUM_ITEMS
#define DIM       64
#define NNZ_C     10000000
#define BATCH_C   4096
#define NCHUNKS   147      // ceil(150000 / 1024)

// ---------------- CSR build ----------------

__global__ __launch_bounds__(256) void count_kernel(const int4* __restrict__ dst4,
                                                    int* __restrict__ cnt) {
    int i = blockIdx.x * blockDim.x + threadIdx.x;
    int stride = gridDim.x * blockDim.x;
    const int N4 = NNZ_C / 4;
    for (; i < N4; i += stride) {
        int4 d = dst4[i];
        atomicAdd(&cnt[d.x], 1);   // fire-and-forget: no return dependency
        atomicAdd(&cnt[d.y], 1);
        atomicAdd(&cnt[d.z], 1);
        atomicAdd(&cnt[d.w], 1);
    }
}

// Per-chunk (1024 elems) exclusive scan; chunk totals out.
__global__ __launch_bounds__(256) void scanA_kernel(const int* __restrict__ cnt,
                                                    int* __restrict__ row_ptr,
                                                    int* __restrict__ chunk_sums) {
    __shared__ int sh[256];
    int b = blockIdx.x, t = threadIdx.x;
    int base = b * 1024 + t * 4;
    int v0 = (base + 0 < N_NODES) ? cnt[base + 0] : 0;
    int v1 = (base + 1 < N_NODES) ? cnt[base + 1] : 0;
    int v2 = (base + 2 < N_NODES) ? cnt[base + 2] : 0;
    int v3 = (base + 3 < N_NODES) ? cnt[base + 3] : 0;
    int s = v0 + v1 + v2 + v3;
    sh[t] = s;
    __syncthreads();
    for (int off = 1; off < 256; off <<= 1) {
        int x = (t >= off) ? sh[t - off] : 0;
        __syncthreads();
        sh[t] += x;
        __syncthreads();
    }
    int excl = sh[t] - s;
    if (t == 255) chunk_sums[b] = sh[255];
    int run = excl;
    if (base + 0 < N_NODES) { row_ptr[base + 0] = run; run += v0; }
    if (base + 1 < N_NODES) { row_ptr[base + 1] = run; run += v1; }
    if (base + 2 < N_NODES) { row_ptr[base + 2] = run; run += v2; }
    if (base + 3 < N_NODES) { row_ptr[base + 3] = run; run += v3; }
}

__global__ void scanB_kernel(int* __restrict__ chunk_sums) {
    if (threadIdx.x == 0 && blockIdx.x == 0) {
        int run = 0;
        for (int i = 0; i < NCHUNKS; ++i) {
            int c = chunk_sums[i];
            chunk_sums[i] = run;
            run += c;
        }
    }
}

__global__ __launch_bounds__(256) void scanC_kernel(int* __restrict__ row_ptr,
                                                    int* __restrict__ cursor,
                                                    const int* __restrict__ chunk_offs) {
    int i = blockIdx.x * blockDim.x + threadIdx.x;
    if (i < N_NODES) {
        int v = row_ptr[i] + chunk_offs[i >> 10];
        row_ptr[i] = v;
        cursor[i] = v;
    } else if (i == N_NODES) {
        row_ptr[i] = NNZ_C;
    }
}

// 4-way unrolled: 4 independent atomics in flight before the dependent stores.
__global__ __launch_bounds__(256) void scatter_kernel(const int* __restrict__ src,
                                                      const int* __restrict__ dst,
                                                      const float* __restrict__ val,
                                                      int2* __restrict__ packed,
                                                      int* __restrict__ cursor) {
    int stride = gridDim.x * blockDim.x;
    int i = blockIdx.x * blockDim.x + threadIdx.x;
    for (; i < NNZ_C; i += 4 * stride) {
        int j1 = i + stride, j2 = i + 2 * stride, j3 = i + 3 * stride;
        bool b1 = j1 < NNZ_C, b2 = j2 < NNZ_C, b3 = j3 < NNZ_C;
        int d0 = dst[i];
        int s0 = src[i];
        float v0 = val[i];
        int d1 = 0, s1 = 0; float v1 = 0.f;
        int d2 = 0, s2 = 0; float v2 = 0.f;
        int d3 = 0, s3 = 0; float v3 = 0.f;
        if (b1) { d1 = dst[j1]; s1 = src[j1]; v1 = val[j1]; }
        if (b2) { d2 = dst[j2]; s2 = src[j2]; v2 = val[j2]; }
        if (b3) { d3 = dst[j3]; s3 = src[j3]; v3 = val[j3]; }
        int p0 = atomicAdd(&cursor[d0], 1);
        int p1 = b1 ? atomicAdd(&cursor[d1], 1) : 0;
        int p2 = b2 ? atomicAdd(&cursor[d2], 1) : 0;
        int p3 = b3 ? atomicAdd(&cursor[d3], 1) : 0;
        packed[p0] = make_int2(s0, __float_as_int(v0));
        if (b1) packed[p1] = make_int2(s1, __float_as_int(v1));
        if (b2) packed[p2] = make_int2(s2, __float_as_int(v2));
        if (b3) packed[p3] = make_int2(s3, __float_as_int(v3));
    }
}

// ---------------- X = concat(uemb, iemb) ----------------

__global__ __launch_bounds__(256) void concat_kernel(const float* __restrict__ uemb,
                                                     const float* __restrict__ iemb,
                                                     float4* __restrict__ X4) {
    const int NU4 = NUM_USERS * DIM / 4;   // 1,600,000
    const int NT4 = N_NODES * DIM / 4;     // 2,400,000
    int i = blockIdx.x * blockDim.x + threadIdx.x;
    int stride = gridDim.x * blockDim.x;
    const float4* u4 = (const float4*)uemb;
    const float4* i4 = (const float4*)iemb;
    for (; i < NT4; i += stride)
        X4[i] = (i < NU4) ? u4[i] : i4[i - NU4];
}

// ---------------- SpMM (gather, 1 wave per dst node, quad-edge float4) ----
// lane = (q = lane>>4: edge slot, d4 = lane&15: dim quad). Each wave-wide
// float4 gather fetches 4 edges' rows (1 KB). Edge (s,v) broadcast via
// ds_bpermute. Epilogue: shfl_xor reduce over the 4 edge-slot groups.

__global__ __launch_bounds__(256) void spmm_kernel(const int2* __restrict__ packed,
                                                   const int* __restrict__ row_ptr,
                                                   const float* __restrict__ xin,
                                                   float* __restrict__ xout) {
    int gtid = blockIdx.x * blockDim.x + threadIdx.x;
    int node = gtid >> 6;
    int lane = threadIdx.x & 63;
    if (node >= N_NODES) return;
    int beg = row_ptr[node];
    int end = row_ptr[node + 1];
    int q  = lane >> 4;
    int d4 = lane & 15;
    const float4* xbase = (const float4*)xin + d4;   // xbase[16*s] = row s, dims 4*d4..
    float4 acc = make_float4(0.f, 0.f, 0.f, 0.f);

    for (int base = beg; base < end; base += 64) {
        int n = end - base;
        n = n > 64 ? 64 : n;
        int2 p = make_int2(0, 0);
        if (lane < n) p = packed[base + lane];   // zero-pad: v=0 contributes nothing
        if (n == 64) {
            #pragma unroll
            for (int t = 0; t < 16; ++t) {
                int srclane = (4 * t + q) << 2;
                int s  = __builtin_amdgcn_ds_bpermute(srclane, p.x);
                float v = __int_as_float(__builtin_amdgcn_ds_bpermute(srclane, p.y));
                float4 r = xbase[s * 16];
                acc.x = fmaf(v, r.x, acc.x);
                acc.y = fmaf(v, r.y, acc.y);
                acc.z = fmaf(v, r.z, acc.z);
                acc.w = fmaf(v, r.w, acc.w);
            }
        } else {
            int nq = (n + 3) >> 2;
            #pragma unroll 4
            for (int t = 0; t < nq; ++t) {
                int srclane = (4 * t + q) << 2;
                int s  = __builtin_amdgcn_ds_bpermute(srclane, p.x);
                float v = __int_as_float(__builtin_amdgcn_ds_bpermute(srclane, p.y));
                float4 r = xbase[s * 16];
                acc.x = fmaf(v, r.x, acc.x);
                acc.y = fmaf(v, r.y, acc.y);
                acc.z = fmaf(v, r.z, acc.z);
                acc.w = fmaf(v, r.w, acc.w);
            }
        }
    }
    // reduce across edge-slot groups (lanes l, l^16, l^32, l^48)
    acc.x += __shfl_xor(acc.x, 16);
    acc.y += __shfl_xor(acc.y, 16);
    acc.z += __shfl_xor(acc.z, 16);
    acc.w += __shfl_xor(acc.w, 16);
    acc.x += __shfl_xor(acc.x, 32);
    acc.y += __shfl_xor(acc.y, 32);
    acc.z += __shfl_xor(acc.z, 32);
    acc.w += __shfl_xor(acc.w, 32);
    if (lane < 16)
        ((float4*)(xout + (size_t)node * DIM))[d4] = acc;
}

// ---------------- selected-row accumulation + dot ----------------

__global__ __launch_bounds__(256) void init_sel_kernel(const int* __restrict__ users,
                                                       const int* __restrict__ items,
                                                       const float* __restrict__ X,
                                                       float* __restrict__ acc_sel) {
    int gtid = blockIdx.x * blockDim.x + threadIdx.x;
    int idx = gtid >> 4;            // row
    int l = threadIdx.x & 15;       // dim quad
    if (idx >= 2 * BATCH_C) return;
    int node = (idx < BATCH_C) ? users[idx] : (NUM_USERS + items[idx - BATCH_C]);
    ((float4*)(acc_sel + (size_t)idx * DIM))[l] =
        ((const float4*)(X + (size_t)node * DIM))[l];
}

__global__ __launch_bounds__(256) void add_sel_kernel(const int* __restrict__ users,
                                                      const int* __restrict__ items,
                                                      const float* __restrict__ h,
                                                      float* __restrict__ acc_sel) {
    int gtid = blockIdx.x * blockDim.x + threadIdx.x;
    int idx = gtid >> 4;
    int l = threadIdx.x & 15;
    if (idx >= 2 * BATCH_C) return;
    int node = (idx < BATCH_C) ? users[idx] : (NUM_USERS + items[idx - BATCH_C]);
    float4 a = ((float4*)(acc_sel + (size_t)idx * DIM))[l];
    float4 b = ((const float4*)(h + (size_t)node * DIM))[l];
    a.x += b.x; a.y += b.y; a.z += b.z; a.w += b.w;
    ((float4*)(acc_sel + (size_t)idx * DIM))[l] = a;
}

__global__ __launch_bounds__(256) void dot_kernel(const float* __restrict__ acc_sel,
                                                  float* __restrict__ out) {
    int gtid = blockIdx.x * blockDim.x + threadIdx.x;
    int b = gtid >> 6;
    int lane = threadIdx.x & 63;
    if (b >= BATCH_C) return;
    float u = acc_sel[(size_t)b * DIM + lane];
    float v = acc_sel[(size_t)(BATCH_C + b) * DIM + lane];
    float p = u * v;
    for (int off = 32; off > 0; off >>= 1) p += __shfl_xor(p, off);
    if (lane == 0) out[b] = p * 0.0625f;  // (1/4)^2 for the two light_out rows
}

// ---------------- launch ----------------

extern "C" void kernel_launch(void* const* d_in, const int* in_sizes, int n_in,
                              void* d_out, int out_size, void* d_ws, size_t ws_size,
                              hipStream_t stream) {
    const int*   users = (const int*)d_in[0];
    const int*   items = (const int*)d_in[1];
    const float* uemb  = (const float*)d_in[2];
    const float* iemb  = (const float*)d_in[3];
    const int*   esrc  = (const int*)d_in[4];
    const int*   edst  = (const int*)d_in[5];
    const float* eval  = (const float*)d_in[6];
    float*       out   = (float*)d_out;

    char* ws = (char*)d_ws;
    int2*  packed   = (int2*)(ws + 0);             // 80,000,000
    float* X        = (float*)(ws + 80000000);     // 38,400,000
    float* hA       = (float*)(ws + 118400000);    // 38,400,000
    float* acc_sel  = (float*)(ws + 156800000);    // 2,097,152
    int*   row_ptr  = (int*)(ws + 158897152);      // 600,004
    int*   cursor   = (int*)(ws + 159497168);      // 600,000
    int*   chunk_s  = (int*)(ws + 160097168);      // 1,024
    // total ~160.1 MB (known to fit ws)

    // 1) CSR build (edge structure shared by all 3 layers)
    hipMemsetAsync(cursor, 0, N_NODES * sizeof(int), stream);
    count_kernel<<<2048, 256, 0, stream>>>((const int4*)edst, cursor);
    scanA_kernel<<<NCHUNKS, 256, 0, stream>>>(cursor, row_ptr, chunk_s);
    scanB_kernel<<<1, 64, 0, stream>>>(chunk_s);
    scanC_kernel<<<(N_NODES + 256) / 256, 256, 0, stream>>>(row_ptr, cursor, chunk_s);
    scatter_kernel<<<2048, 256, 0, stream>>>(esrc, edst, eval, packed, cursor);

    // 2) X = concat(uemb, iemb); selected-row init (layer-0 term)
    concat_kernel<<<2048, 256, 0, stream>>>(uemb, iemb, (float4*)X);
    init_sel_kernel<<<(2 * BATCH_C * 16 + 255) / 256, 256, 0, stream>>>(users, items, X, acc_sel);

    // 3) three SpMM layers; accumulate selected rows after each.
    const int spmm_blocks = N_NODES / 4;  // 1 wave per node, 4 waves per block
    spmm_kernel<<<spmm_blocks, 256, 0, stream>>>(packed, row_ptr, X, hA);
    add_sel_kernel<<<(2 * BATCH_C * 16 + 255) / 256, 256, 0, stream>>>(users, items, hA, acc_sel);
    spmm_kernel<<<spmm_blocks, 256, 0, stream>>>(packed, row_ptr, hA, X);
    add_sel_kernel<<<(2 * BATCH_C * 16 + 255) / 256, 256, 0, stream>>>(users, items, X, acc_sel);
    spmm_kernel<<<spmm_blocks, 256, 0, stream>>>(packed, row_ptr, X, hA);
    add_sel_kernel<<<(2 * BATCH_C * 16 + 255) / 256, 256, 0, stream>>>(users, items, hA, acc_sel);

    // 4) final dot products
    dot_kernel<<<BATCH_C / 4, 256, 0, stream>>>(acc_sel, out);
}

// Round 7
// 1960.333 us; speedup vs baseline: 1.1660x; 1.1660x over previous
//
#include <hip/hip_runtime.h>

#define NUM_USERS 100000
#define NUM_ITEMS 50000
#define N_NODES   150000   // NUM_USERS + NUM_ITEMS
#define DIM       64
#define NNZ_C     10000000
#define BATCH_C   4096
#define NCHUNKS   147      // ceil(150000 / 1024)

// ---------------- CSR build ----------------

__global__ __launch_bounds__(256) void count_kernel(const int4* __restrict__ dst4,
                                                    int* __restrict__ cnt) {
    int i = blockIdx.x * blockDim.x + threadIdx.x;
    int stride = gridDim.x * blockDim.x;
    const int N4 = NNZ_C / 4;
    for (; i < N4; i += stride) {
        int4 d = dst4[i];
        atomicAdd(&cnt[d.x], 1);   // fire-and-forget: no return dependency
        atomicAdd(&cnt[d.y], 1);
        atomicAdd(&cnt[d.z], 1);
        atomicAdd(&cnt[d.w], 1);
    }
}

// Per-chunk (1024 elems) exclusive scan; chunk totals out.
__global__ __launch_bounds__(256) void scanA_kernel(const int* __restrict__ cnt,
                                                    int* __restrict__ row_ptr,
                                                    int* __restrict__ chunk_sums) {
    __shared__ int sh[256];
    int b = blockIdx.x, t = threadIdx.x;
    int base = b * 1024 + t * 4;
    int v0 = (base + 0 < N_NODES) ? cnt[base + 0] : 0;
    int v1 = (base + 1 < N_NODES) ? cnt[base + 1] : 0;
    int v2 = (base + 2 < N_NODES) ? cnt[base + 2] : 0;
    int v3 = (base + 3 < N_NODES) ? cnt[base + 3] : 0;
    int s = v0 + v1 + v2 + v3;
    sh[t] = s;
    __syncthreads();
    for (int off = 1; off < 256; off <<= 1) {
        int x = (t >= off) ? sh[t - off] : 0;
        __syncthreads();
        sh[t] += x;
        __syncthreads();
    }
    int excl = sh[t] - s;
    if (t == 255) chunk_sums[b] = sh[255];
    int run = excl;
    if (base + 0 < N_NODES) { row_ptr[base + 0] = run; run += v0; }
    if (base + 1 < N_NODES) { row_ptr[base + 1] = run; run += v1; }
    if (base + 2 < N_NODES) { row_ptr[base + 2] = run; run += v2; }
    if (base + 3 < N_NODES) { row_ptr[base + 3] = run; run += v3; }
}

__global__ void scanB_kernel(int* __restrict__ chunk_sums) {
    if (threadIdx.x == 0 && blockIdx.x == 0) {
        int run = 0;
        for (int i = 0; i < NCHUNKS; ++i) {
            int c = chunk_sums[i];
            chunk_sums[i] = run;
            run += c;
        }
    }
}

__global__ __launch_bounds__(256) void scanC_kernel(int* __restrict__ row_ptr,
                                                    int* __restrict__ cursor,
                                                    const int* __restrict__ chunk_offs) {
    int i = blockIdx.x * blockDim.x + threadIdx.x;
    if (i < N_NODES) {
        int v = row_ptr[i] + chunk_offs[i >> 10];
        row_ptr[i] = v;
        cursor[i] = v;
    } else if (i == N_NODES) {
        row_ptr[i] = NNZ_C;
    }
}

// Round-3 form (measured 490 us): single dependent chain per thread, ~19 iters.
// 4-way unroll REGRESSED to 820 us (device-atomic queue saturation) — keep simple.
__global__ __launch_bounds__(256) void scatter_kernel(const int* __restrict__ src,
                                                      const int* __restrict__ dst,
                                                      const float* __restrict__ val,
                                                      int2* __restrict__ packed,
                                                      int* __restrict__ cursor) {
    int i = blockIdx.x * blockDim.x + threadIdx.x;
    int stride = gridDim.x * blockDim.x;
    for (; i < NNZ_C; i += stride) {
        int d = dst[i];
        int p = atomicAdd(&cursor[d], 1);
        packed[p] = make_int2(src[i], __float_as_int(val[i]));
    }
}

// ---------------- X = concat(uemb, iemb) ----------------

__global__ __launch_bounds__(256) void concat_kernel(const float* __restrict__ uemb,
                                                     const float* __restrict__ iemb,
                                                     float4* __restrict__ X4) {
    const int NU4 = NUM_USERS * DIM / 4;   // 1,600,000
    const int NT4 = N_NODES * DIM / 4;     // 2,400,000
    int i = blockIdx.x * blockDim.x + threadIdx.x;
    int stride = gridDim.x * blockDim.x;
    const float4* u4 = (const float4*)uemb;
    const float4* i4 = (const float4*)iemb;
    for (; i < NT4; i += stride)
        X4[i] = (i < NU4) ? u4[i] : i4[i - NU4];
}

// ---------------- SpMM (gather, 1 wave per dst node, quad-edge float4) ----
// lane = (q = lane>>4: edge slot, d4 = lane&15: dim quad). Each wave-wide
// float4 gather fetches 4 edges' rows (1 KB). Edge (s,v) broadcast via
// ds_bpermute. Epilogue: shfl_xor reduce over the 4 edge-slot groups.

__global__ __launch_bounds__(256) void spmm_kernel(const int2* __restrict__ packed,
                                                   const int* __restrict__ row_ptr,
                                                   const float* __restrict__ xin,
                                                   float* __restrict__ xout) {
    int gtid = blockIdx.x * blockDim.x + threadIdx.x;
    int node = gtid >> 6;
    int lane = threadIdx.x & 63;
    if (node >= N_NODES) return;
    int beg = row_ptr[node];
    int end = row_ptr[node + 1];
    int q  = lane >> 4;
    int d4 = lane & 15;
    const float4* xbase = (const float4*)xin + d4;   // xbase[16*s] = row s, dims 4*d4..
    float4 acc = make_float4(0.f, 0.f, 0.f, 0.f);

    for (int base = beg; base < end; base += 64) {
        int n = end - base;
        n = n > 64 ? 64 : n;
        int2 p = make_int2(0, 0);
        if (lane < n) p = packed[base + lane];   // zero-pad: v=0 contributes nothing
        if (n == 64) {
            #pragma unroll
            for (int t = 0; t < 16; ++t) {
                int srclane = (4 * t + q) << 2;
                int s  = __builtin_amdgcn_ds_bpermute(srclane, p.x);
                float v = __int_as_float(__builtin_amdgcn_ds_bpermute(srclane, p.y));
                float4 r = xbase[s * 16];
                acc.x = fmaf(v, r.x, acc.x);
                acc.y = fmaf(v, r.y, acc.y);
                acc.z = fmaf(v, r.z, acc.z);
                acc.w = fmaf(v, r.w, acc.w);
            }
        } else {
            int nq = (n + 3) >> 2;
            #pragma unroll 4
            for (int t = 0; t < nq; ++t) {
                int srclane = (4 * t + q) << 2;
                int s  = __builtin_amdgcn_ds_bpermute(srclane, p.x);
                float v = __int_as_float(__builtin_amdgcn_ds_bpermute(srclane, p.y));
                float4 r = xbase[s * 16];
                acc.x = fmaf(v, r.x, acc.x);
                acc.y = fmaf(v, r.y, acc.y);
                acc.z = fmaf(v, r.z, acc.z);
                acc.w = fmaf(v, r.w, acc.w);
            }
        }
    }
    // reduce across edge-slot groups (lanes l, l^16, l^32, l^48)
    acc.x += __shfl_xor(acc.x, 16);
    acc.y += __shfl_xor(acc.y, 16);
    acc.z += __shfl_xor(acc.z, 16);
    acc.w += __shfl_xor(acc.w, 16);
    acc.x += __shfl_xor(acc.x, 32);
    acc.y += __shfl_xor(acc.y, 32);
    acc.z += __shfl_xor(acc.z, 32);
    acc.w += __shfl_xor(acc.w, 32);
    if (lane < 16)
        ((float4*)(xout + (size_t)node * DIM))[d4] = acc;
}

// ---------------- selected-row accumulation + dot ----------------

__global__ __launch_bounds__(256) void init_sel_kernel(const int* __restrict__ users,
                                                       const int* __restrict__ items,
                                                       const float* __restrict__ X,
                                                       float* __restrict__ acc_sel) {
    int gtid = blockIdx.x * blockDim.x + threadIdx.x;
    int idx = gtid >> 4;            // row
    int l = threadIdx.x & 15;       // dim quad
    if (idx >= 2 * BATCH_C) return;
    int node = (idx < BATCH_C) ? users[idx] : (NUM_USERS + items[idx - BATCH_C]);
    ((float4*)(acc_sel + (size_t)idx * DIM))[l] =
        ((const float4*)(X + (size_t)node * DIM))[l];
}

__global__ __launch_bounds__(256) void add_sel_kernel(const int* __restrict__ users,
                                                      const int* __restrict__ items,
                                                      const float* __restrict__ h,
                                                      float* __restrict__ acc_sel) {
    int gtid = blockIdx.x * blockDim.x + threadIdx.x;
    int idx = gtid >> 4;
    int l = threadIdx.x & 15;
    if (idx >= 2 * BATCH_C) return;
    int node = (idx < BATCH_C) ? users[idx] : (NUM_USERS + items[idx - BATCH_C]);
    float4 a = ((float4*)(acc_sel + (size_t)idx * DIM))[l];
    float4 b = ((const float4*)(h + (size_t)node * DIM))[l];
    a.x += b.x; a.y += b.y; a.z += b.z; a.w += b.w;
    ((float4*)(acc_sel + (size_t)idx * DIM))[l] = a;
}

__global__ __launch_bounds__(256) void dot_kernel(const float* __restrict__ acc_sel,
                                                  float* __restrict__ out) {
    int gtid = blockIdx.x * blockDim.x + threadIdx.x;
    int b = gtid >> 6;
    int lane = threadIdx.x & 63;
    if (b >= BATCH_C) return;
    float u = acc_sel[(size_t)b * DIM + lane];
    float v = acc_sel[(size_t)(BATCH_C + b) * DIM + lane];
    float p = u * v;
    for (int off = 32; off > 0; off >>= 1) p += __shfl_xor(p, off);
    if (lane == 0) out[b] = p * 0.0625f;  // (1/4)^2 for the two light_out rows
}

// ---------------- launch ----------------

extern "C" void kernel_launch(void* const* d_in, const int* in_sizes, int n_in,
                              void* d_out, int out_size, void* d_ws, size_t ws_size,
                              hipStream_t stream) {
    const int*   users = (const int*)d_in[0];
    const int*   items = (const int*)d_in[1];
    const float* uemb  = (const float*)d_in[2];
    const float* iemb  = (const float*)d_in[3];
    const int*   esrc  = (const int*)d_in[4];
    const int*   edst  = (const int*)d_in[5];
    const float* eval  = (const float*)d_in[6];
    float*       out   = (float*)d_out;

    char* ws = (char*)d_ws;
    int2*  packed   = (int2*)(ws + 0);             // 80,000,000
    float* X        = (float*)(ws + 80000000);     // 38,400,000
    float* hA       = (float*)(ws + 118400000);    // 38,400,000
    float* acc_sel  = (float*)(ws + 156800000);    // 2,097,152
    int*   row_ptr  = (int*)(ws + 158897152);      // 600,004
    int*   cursor   = (int*)(ws + 159497168);      // 600,000
    int*   chunk_s  = (int*)(ws + 160097168);      // 1,024
    // total ~160.1 MB (known to fit ws)

    // 1) CSR build (edge structure shared by all 3 layers)
    hipMemsetAsync(cursor, 0, N_NODES * sizeof(int), stream);
    count_kernel<<<2048, 256, 0, stream>>>((const int4*)edst, cursor);
    scanA_kernel<<<NCHUNKS, 256, 0, stream>>>(cursor, row_ptr, chunk_s);
    scanB_kernel<<<1, 64, 0, stream>>>(chunk_s);
    scanC_kernel<<<(N_NODES + 256) / 256, 256, 0, stream>>>(row_ptr, cursor, chunk_s);
    scatter_kernel<<<2048, 256, 0, stream>>>(esrc, edst, eval, packed, cursor);

    // 2) X = concat(uemb, iemb); selected-row init (layer-0 term)
    concat_kernel<<<2048, 256, 0, stream>>>(uemb, iemb, (float4*)X);
    init_sel_kernel<<<(2 * BATCH_C * 16 + 255) / 256, 256, 0, stream>>>(users, items, X, acc_sel);

    // 3) three SpMM layers; accumulate selected rows after each.
    const int spmm_blocks = N_NODES / 4;  // 1 wave per node, 4 waves per block
    spmm_kernel<<<spmm_blocks, 256, 0, stream>>>(packed, row_ptr, X, hA);
    add_sel_kernel<<<(2 * BATCH_C * 16 + 255) / 256, 256, 0, stream>>>(users, items, hA, acc_sel);
    spmm_kernel<<<spmm_blocks, 256, 0, stream>>>(packed, row_ptr, hA, X);
    add_sel_kernel<<<(2 * BATCH_C * 16 + 255) / 256, 256, 0, stream>>>(users, items, X, acc_sel);
    spmm_kernel<<<spmm_blocks, 256, 0, stream>>>(packed, row_ptr, X, hA);
    add_sel_kernel<<<(2 * BATCH_C * 16 + 255) / 256, 256, 0, stream>>>(users, items, hA, acc_sel);

    // 4) final dot products
    dot_kernel<<<BATCH_C / 4, 256, 0, stream>>>(acc_sel, out);
}

// Round 10
// 1669.737 us; speedup vs baseline: 1.3690x; 1.1740x over previous
//
#include <hip/hip_runtime.h>

#define NUM_USERS 100000
#define NUM_ITEMS 50000
#define N_NODES   150000   // NUM_USERS + NUM_ITEMS
#define DIM       64
#define NNZ_C     10000000
#define BATCH_C   4096
#define NCHUNKS   147      // ceil(150000 / 1024)

// ---------------- CSR build ----------------

__global__ __launch_bounds__(256) void count_kernel(const int4* __restrict__ dst4,
                                                    int* __restrict__ cnt) {
    int i = blockIdx.x * blockDim.x + threadIdx.x;
    int stride = gridDim.x * blockDim.x;
    const int N4 = NNZ_C / 4;
    for (; i < N4; i += stride) {
        int4 d = dst4[i];
        atomicAdd(&cnt[d.x], 1);   // fire-and-forget: no return dependency
        atomicAdd(&cnt[d.y], 1);
        atomicAdd(&cnt[d.z], 1);
        atomicAdd(&cnt[d.w], 1);
    }
}

// Per-chunk (1024 elems) exclusive scan; chunk totals out.
__global__ __launch_bounds__(256) void scanA_kernel(const int* __restrict__ cnt,
                                                    int* __restrict__ row_ptr,
                                                    int* __restrict__ chunk_sums) {
    __shared__ int sh[256];
    int b = blockIdx.x, t = threadIdx.x;
    int base = b * 1024 + t * 4;
    int v0 = (base + 0 < N_NODES) ? cnt[base + 0] : 0;
    int v1 = (base + 1 < N_NODES) ? cnt[base + 1] : 0;
    int v2 = (base + 2 < N_NODES) ? cnt[base + 2] : 0;
    int v3 = (base + 3 < N_NODES) ? cnt[base + 3] : 0;
    int s = v0 + v1 + v2 + v3;
    sh[t] = s;
    __syncthreads();
    for (int off = 1; off < 256; off <<= 1) {
        int x = (t >= off) ? sh[t - off] : 0;
        __syncthreads();
        sh[t] += x;
        __syncthreads();
    }
    int excl = sh[t] - s;
    if (t == 255) chunk_sums[b] = sh[255];
    int run = excl;
    if (base + 0 < N_NODES) { row_ptr[base + 0] = run; run += v0; }
    if (base + 1 < N_NODES) { row_ptr[base + 1] = run; run += v1; }
    if (base + 2 < N_NODES) { row_ptr[base + 2] = run; run += v2; }
    if (base + 3 < N_NODES) { row_ptr[base + 3] = run; run += v3; }
}

__global__ void scanB_kernel(int* __restrict__ chunk_sums) {
    if (threadIdx.x == 0 && blockIdx.x == 0) {
        int run = 0;
        for (int i = 0; i < NCHUNKS; ++i) {
            int c = chunk_sums[i];
            chunk_sums[i] = run;
            run += c;
        }
    }
}

__global__ __launch_bounds__(256) void scanC_kernel(int* __restrict__ row_ptr,
                                                    int* __restrict__ cursor,
                                                    const int* __restrict__ chunk_offs) {
    int i = blockIdx.x * blockDim.x + threadIdx.x;
    if (i < N_NODES) {
        int v = row_ptr[i] + chunk_offs[i >> 10];
        row_ptr[i] = v;
        cursor[i] = v;
    } else if (i == N_NODES) {
        row_ptr[i] = NNZ_C;
    }
}

// Round-3 form (measured 490 us): single dependent chain per thread, ~19 iters.
// 4-way unroll REGRESSED to 820 us (device-atomic queue saturation) — keep simple.
__global__ __launch_bounds__(256) void scatter_kernel(const int* __restrict__ src,
                                                      const int* __restrict__ dst,
                                                      const float* __restrict__ val,
                                                      int2* __restrict__ packed,
                                                      int* __restrict__ cursor) {
    int i = blockIdx.x * blockDim.x + threadIdx.x;
    int stride = gridDim.x * blockDim.x;
    for (; i < NNZ_C; i += stride) {
        int d = dst[i];
        int p = atomicAdd(&cursor[d], 1);
        packed[p] = make_int2(src[i], __float_as_int(val[i]));
    }
}

// ---------------- X = concat(uemb, iemb) ----------------

__global__ __launch_bounds__(256) void concat_kernel(const float* __restrict__ uemb,
                                                     const float* __restrict__ iemb,
                                                     float4* __restrict__ X4) {
    const int NU4 = NUM_USERS * DIM / 4;   // 1,600,000
    const int NT4 = N_NODES * DIM / 4;     // 2,400,000
    int i = blockIdx.x * blockDim.x + threadIdx.x;
    int stride = gridDim.x * blockDim.x;
    const float4* u4 = (const float4*)uemb;
    const float4* i4 = (const float4*)iemb;
    for (; i < NT4; i += stride)
        X4[i] = (i < NU4) ? u4[i] : i4[i - NU4];
}

// ---------------- SpMM (gather, 1 wave per dst node, quad-edge float4) ----
// lane = (q = lane>>4: edge slot, d4 = lane&15: dim quad). Each wave-wide
// float4 gather fetches 4 edges' rows (1 KB). Edge (s,v) broadcast via
// ds_bpermute. Epilogue: shfl_xor reduce over the 4 edge-slot groups.

__global__ __launch_bounds__(256) void spmm_kernel(const int2* __restrict__ packed,
                                                   const int* __restrict__ row_ptr,
                                                   const float* __restrict__ xin,
                                                   float* __restrict__ xout) {
    int gtid = blockIdx.x * blockDim.x + threadIdx.x;
    int node = gtid >> 6;
    int lane = threadIdx.x & 63;
    if (node >= N_NODES) return;
    int beg = row_ptr[node];
    int end = row_ptr[node + 1];
    int q  = lane >> 4;
    int d4 = lane & 15;
    const float4* xbase = (const float4*)xin + d4;   // xbase[16*s] = row s, dims 4*d4..
    float4 acc = make_float4(0.f, 0.f, 0.f, 0.f);

    for (int base = beg; base < end; base += 64) {
        int n = end - base;
        n = n > 64 ? 64 : n;
        int2 p = make_int2(0, 0);
        if (lane < n) p = packed[base + lane];   // zero-pad: v=0 contributes nothing
        if (n == 64) {
            #pragma unroll
            for (int t = 0; t < 16; ++t) {
                int srclane = (4 * t + q) << 2;
                int s  = __builtin_amdgcn_ds_bpermute(srclane, p.x);
                float v = __int_as_float(__builtin_amdgcn_ds_bpermute(srclane, p.y));
                float4 r = xbase[s * 16];
                acc.x = fmaf(v, r.x, acc.x);
                acc.y = fmaf(v, r.y, acc.y);
                acc.z = fmaf(v, r.z, acc.z);
                acc.w = fmaf(v, r.w, acc.w);
            }
        } else {
            int nq = (n + 3) >> 2;
            #pragma unroll 4
            for (int t = 0; t < nq; ++t) {
                int srclane = (4 * t + q) << 2;
                int s  = __builtin_amdgcn_ds_bpermute(srclane, p.x);
                float v = __int_as_float(__builtin_amdgcn_ds_bpermute(srclane, p.y));
                float4 r = xbase[s * 16];
                acc.x = fmaf(v, r.x, acc.x);
                acc.y = fmaf(v, r.y, acc.y);
                acc.z = fmaf(v, r.z, acc.z);
                acc.w = fmaf(v, r.w, acc.w);
            }
        }
    }
    // reduce across edge-slot groups (lanes l, l^16, l^32, l^48)
    acc.x += __shfl_xor(acc.x, 16);
    acc.y += __shfl_xor(acc.y, 16);
    acc.z += __shfl_xor(acc.z, 16);
    acc.w += __shfl_xor(acc.w, 16);
    acc.x += __shfl_xor(acc.x, 32);
    acc.y += __shfl_xor(acc.y, 32);
    acc.z += __shfl_xor(acc.z, 32);
    acc.w += __shfl_xor(acc.w, 32);
    if (lane < 16)
        ((float4*)(xout + (size_t)node * DIM))[d4] = acc;
}

// ---------------- restricted layer-3 SpMM: one wave per batch slot --------
// h3 is only needed at the 8192 selected rows; walk those CSR rows over h2
// and accumulate straight into acc_sel. ~550K edges instead of 10M.

__global__ __launch_bounds__(256) void spmm_sel_kernel(const int2* __restrict__ packed,
                                                       const int* __restrict__ row_ptr,
                                                       const int* __restrict__ users,
                                                       const int* __restrict__ items,
                                                       const float* __restrict__ h2,
                                                       float* __restrict__ acc_sel) {
    int gtid = blockIdx.x * blockDim.x + threadIdx.x;
    int slot = gtid >> 6;
    int lane = threadIdx.x & 63;
    if (slot >= 2 * BATCH_C) return;
    int node = (slot < BATCH_C) ? users[slot] : (NUM_USERS + items[slot - BATCH_C]);
    int beg = row_ptr[node];
    int end = row_ptr[node + 1];
    int q  = lane >> 4;
    int d4 = lane & 15;
    const float4* xbase = (const float4*)h2 + d4;
    float4 acc = make_float4(0.f, 0.f, 0.f, 0.f);

    for (int base = beg; base < end; base += 64) {
        int n = end - base;
        n = n > 64 ? 64 : n;
        int2 p = make_int2(0, 0);
        if (lane < n) p = packed[base + lane];
        int nq = (n + 3) >> 2;
        #pragma unroll 4
        for (int t = 0; t < nq; ++t) {
            int srclane = (4 * t + q) << 2;
            int s  = __builtin_amdgcn_ds_bpermute(srclane, p.x);
            float v = __int_as_float(__builtin_amdgcn_ds_bpermute(srclane, p.y));
            float4 r = xbase[s * 16];
            acc.x = fmaf(v, r.x, acc.x);
            acc.y = fmaf(v, r.y, acc.y);
            acc.z = fmaf(v, r.z, acc.z);
            acc.w = fmaf(v, r.w, acc.w);
        }
    }
    acc.x += __shfl_xor(acc.x, 16);
    acc.y += __shfl_xor(acc.y, 16);
    acc.z += __shfl_xor(acc.z, 16);
    acc.w += __shfl_xor(acc.w, 16);
    acc.x += __shfl_xor(acc.x, 32);
    acc.y += __shfl_xor(acc.y, 32);
    acc.z += __shfl_xor(acc.z, 32);
    acc.w += __shfl_xor(acc.w, 32);
    if (lane < 16) {
        float4* dst4 = (float4*)(acc_sel + (size_t)slot * DIM) + d4;
        float4 a = *dst4;
        a.x += acc.x; a.y += acc.y; a.z += acc.z; a.w += acc.w;
        *dst4 = a;
    }
}

// ---------------- selected-row accumulation + dot ----------------

__global__ __launch_bounds__(256) void init_sel_kernel(const int* __restrict__ users,
                                                       const int* __restrict__ items,
                                                       const float* __restrict__ X,
                                                       float* __restrict__ acc_sel) {
    int gtid = blockIdx.x * blockDim.x + threadIdx.x;
    int idx = gtid >> 4;            // row
    int l = threadIdx.x & 15;       // dim quad
    if (idx >= 2 * BATCH_C) return;
    int node = (idx < BATCH_C) ? users[idx] : (NUM_USERS + items[idx - BATCH_C]);
    ((float4*)(acc_sel + (size_t)idx * DIM))[l] =
        ((const float4*)(X + (size_t)node * DIM))[l];
}

__global__ __launch_bounds__(256) void add_sel_kernel(const int* __restrict__ users,
                                                      const int* __restrict__ items,
                                                      const float* __restrict__ h,
                                                      float* __restrict__ acc_sel) {
    int gtid = blockIdx.x * blockDim.x + threadIdx.x;
    int idx = gtid >> 4;
    int l = threadIdx.x & 15;
    if (idx >= 2 * BATCH_C) return;
    int node = (idx < BATCH_C) ? users[idx] : (NUM_USERS + items[idx - BATCH_C]);
    float4 a = ((float4*)(acc_sel + (size_t)idx * DIM))[l];
    float4 b = ((const float4*)(h + (size_t)node * DIM))[l];
    a.x += b.x; a.y += b.y; a.z += b.z; a.w += b.w;
    ((float4*)(acc_sel + (size_t)idx * DIM))[l] = a;
}

__global__ __launch_bounds__(256) void dot_kernel(const float* __restrict__ acc_sel,
                                                  float* __restrict__ out) {
    int gtid = blockIdx.x * blockDim.x + threadIdx.x;
    int b = gtid >> 6;
    int lane = threadIdx.x & 63;
    if (b >= BATCH_C) return;
    float u = acc_sel[(size_t)b * DIM + lane];
    float v = acc_sel[(size_t)(BATCH_C + b) * DIM + lane];
    float p = u * v;
    for (int off = 32; off > 0; off >>= 1) p += __shfl_xor(p, off);
    if (lane == 0) out[b] = p * 0.0625f;  // (1/4)^2 for the two light_out rows
}

// ---------------- launch ----------------

extern "C" void kernel_launch(void* const* d_in, const int* in_sizes, int n_in,
                              void* d_out, int out_size, void* d_ws, size_t ws_size,
                              hipStream_t stream) {
    const int*   users = (const int*)d_in[0];
    const int*   items = (const int*)d_in[1];
    const float* uemb  = (const float*)d_in[2];
    const float* iemb  = (const float*)d_in[3];
    const int*   esrc  = (const int*)d_in[4];
    const int*   edst  = (const int*)d_in[5];
    const float* eval  = (const float*)d_in[6];
    float*       out   = (float*)d_out;

    char* ws = (char*)d_ws;
    int2*  packed   = (int2*)(ws + 0);             // 80,000,000
    float* X        = (float*)(ws + 80000000);     // 38,400,000
    float* hA       = (float*)(ws + 118400000);    // 38,400,000
    float* acc_sel  = (float*)(ws + 156800000);    // 2,097,152
    int*   row_ptr  = (int*)(ws + 158897152);      // 600,004
    int*   cursor   = (int*)(ws + 159497168);      // 600,000
    int*   chunk_s  = (int*)(ws + 160097168);      // 1,024
    // total ~160.1 MB (known to fit ws)

    // 1) CSR build (edge structure shared by all 3 layers)
    hipMemsetAsync(cursor, 0, N_NODES * sizeof(int), stream);
    count_kernel<<<2048, 256, 0, stream>>>((const int4*)edst, cursor);
    scanA_kernel<<<NCHUNKS, 256, 0, stream>>>(cursor, row_ptr, chunk_s);
    scanB_kernel<<<1, 64, 0, stream>>>(chunk_s);
    scanC_kernel<<<(N_NODES + 256) / 256, 256, 0, stream>>>(row_ptr, cursor, chunk_s);
    scatter_kernel<<<2048, 256, 0, stream>>>(esrc, edst, eval, packed, cursor);

    // 2) X = concat(uemb, iemb); selected-row init (layer-0 term)
    concat_kernel<<<2048, 256, 0, stream>>>(uemb, iemb, (float4*)X);
    init_sel_kernel<<<(2 * BATCH_C * 16 + 255) / 256, 256, 0, stream>>>(users, items, X, acc_sel);

    // 3) layers 1,2 full (needed everywhere); layer 3 restricted to batch.
    //    Buffers: X(x0) -> hA(h1) -> X(h2); h3 computed only at selected rows.
    const int spmm_blocks = N_NODES / 4;  // 1 wave per node, 4 waves per block
    spmm_kernel<<<spmm_blocks, 256, 0, stream>>>(packed, row_ptr, X, hA);
    add_sel_kernel<<<(2 * BATCH_C * 16 + 255) / 256, 256, 0, stream>>>(users, items, hA, acc_sel);
    spmm_kernel<<<spmm_blocks, 256, 0, stream>>>(packed, row_ptr, hA, X);
    add_sel_kernel<<<(2 * BATCH_C * 16 + 255) / 256, 256, 0, stream>>>(users, items, X, acc_sel);
    spmm_sel_kernel<<<(2 * BATCH_C) / 4, 256, 0, stream>>>(packed, row_ptr, users, items, X, acc_sel);

    // 4) final dot products
    dot_kernel<<<BATCH_C / 4, 256, 0, stream>>>(acc_sel, out);
}

// Round 11
// 1334.758 us; speedup vs baseline: 1.7125x; 1.2510x over previous
//
#include <hip/hip_runtime.h>

#define NUM_USERS 100000
#define NUM_ITEMS 50000
#define N_NODES   150000   // NUM_USERS + NUM_ITEMS
#define DIM       64
#define NNZ_C     10000000
#define BATCH_C   4096
#define NCHUNKS   147      // ceil(150000 / 1024)
#define CAP       128      // padded bucket capacity; E[max deg] ~107 (7sigma safe)

// ================= shared small kernels =================

__global__ __launch_bounds__(256) void concat_kernel(const float* __restrict__ uemb,
                                                     const float* __restrict__ iemb,
                                                     float4* __restrict__ X4) {
    const int NU4 = NUM_USERS * DIM / 4;   // 1,600,000
    const int NT4 = N_NODES * DIM / 4;     // 2,400,000
    int i = blockIdx.x * blockDim.x + threadIdx.x;
    int stride = gridDim.x * blockDim.x;
    const float4* u4 = (const float4*)uemb;
    const float4* i4 = (const float4*)iemb;
    for (; i < NT4; i += stride)
        X4[i] = (i < NU4) ? u4[i] : i4[i - NU4];
}

__global__ __launch_bounds__(256) void init_sel_kernel(const int* __restrict__ users,
                                                       const int* __restrict__ items,
                                                       const float* __restrict__ X,
                                                       float* __restrict__ acc_sel) {
    int gtid = blockIdx.x * blockDim.x + threadIdx.x;
    int idx = gtid >> 4;            // row
    int l = threadIdx.x & 15;       // dim quad
    if (idx >= 2 * BATCH_C) return;
    int node = (idx < BATCH_C) ? users[idx] : (NUM_USERS + items[idx - BATCH_C]);
    ((float4*)(acc_sel + (size_t)idx * DIM))[l] =
        ((const float4*)(X + (size_t)node * DIM))[l];
}

__global__ __launch_bounds__(256) void add_sel_kernel(const int* __restrict__ users,
                                                      const int* __restrict__ items,
                                                      const float* __restrict__ h,
                                                      float* __restrict__ acc_sel) {
    int gtid = blockIdx.x * blockDim.x + threadIdx.x;
    int idx = gtid >> 4;
    int l = threadIdx.x & 15;
    if (idx >= 2 * BATCH_C) return;
    int node = (idx < BATCH_C) ? users[idx] : (NUM_USERS + items[idx - BATCH_C]);
    float4 a = ((float4*)(acc_sel + (size_t)idx * DIM))[l];
    float4 b = ((const float4*)(h + (size_t)node * DIM))[l];
    a.x += b.x; a.y += b.y; a.z += b.z; a.w += b.w;
    ((float4*)(acc_sel + (size_t)idx * DIM))[l] = a;
}

__global__ __launch_bounds__(256) void dot_kernel(const float* __restrict__ acc_sel,
                                                  float* __restrict__ out) {
    int gtid = blockIdx.x * blockDim.x + threadIdx.x;
    int b = gtid >> 6;
    int lane = threadIdx.x & 63;
    if (b >= BATCH_C) return;
    float u = acc_sel[(size_t)b * DIM + lane];
    float v = acc_sel[(size_t)(BATCH_C + b) * DIM + lane];
    float p = u * v;
    for (int off = 32; off > 0; off >>= 1) p += __shfl_xor(p, off);
    if (lane == 0) out[b] = p * 0.0625f;  // (1/4)^2 for the two light_out rows
}

// ================= PADDED-BUCKET path (no count/scan) =================

// Single-pass bucket scatter: p = atomicAdd(deg[d]); packed[d*CAP+p] = edge.
// Same single-dependent-chain structure as the measured-490us scatter.
__global__ __launch_bounds__(256) void scatterP_kernel(const int* __restrict__ src,
                                                       const int* __restrict__ dst,
                                                       const float* __restrict__ val,
                                                       int2* __restrict__ packed,
                                                       int* __restrict__ deg) {
    int i = blockIdx.x * blockDim.x + threadIdx.x;
    int stride = gridDim.x * blockDim.x;
    for (; i < NNZ_C; i += stride) {
        int d = dst[i];
        int p = atomicAdd(&deg[d], 1);
        if (p < CAP) packed[(size_t)d * CAP + p] = make_int2(src[i], __float_as_int(val[i]));
    }
}

__global__ __launch_bounds__(256) void spmmP_kernel(const int2* __restrict__ packed,
                                                    const int* __restrict__ deg,
                                                    const float* __restrict__ xin,
                                                    float* __restrict__ xout) {
    int gtid = blockIdx.x * blockDim.x + threadIdx.x;
    int node = gtid >> 6;
    int lane = threadIdx.x & 63;
    if (node >= N_NODES) return;
    int nd = deg[node];
    if (nd > CAP) nd = CAP;
    const int2* row = packed + (size_t)node * CAP;
    int q  = lane >> 4;
    int d4 = lane & 15;
    const float4* xbase = (const float4*)xin + d4;
    float4 acc = make_float4(0.f, 0.f, 0.f, 0.f);

    for (int base = 0; base < nd; base += 64) {
        int n = nd - base;
        n = n > 64 ? 64 : n;
        int2 p = make_int2(0, 0);
        if (lane < n) p = row[base + lane];   // zero-pad: v=0 contributes nothing
        if (n == 64) {
            #pragma unroll
            for (int t = 0; t < 16; ++t) {
                int srclane = (4 * t + q) << 2;
                int s  = __builtin_amdgcn_ds_bpermute(srclane, p.x);
                float v = __int_as_float(__builtin_amdgcn_ds_bpermute(srclane, p.y));
                float4 r = xbase[s * 16];
                acc.x = fmaf(v, r.x, acc.x);
                acc.y = fmaf(v, r.y, acc.y);
                acc.z = fmaf(v, r.z, acc.z);
                acc.w = fmaf(v, r.w, acc.w);
            }
        } else {
            int nq = (n + 3) >> 2;
            #pragma unroll 4
            for (int t = 0; t < nq; ++t) {
                int srclane = (4 * t + q) << 2;
                int s  = __builtin_amdgcn_ds_bpermute(srclane, p.x);
                float v = __int_as_float(__builtin_amdgcn_ds_bpermute(srclane, p.y));
                float4 r = xbase[s * 16];
                acc.x = fmaf(v, r.x, acc.x);
                acc.y = fmaf(v, r.y, acc.y);
                acc.z = fmaf(v, r.z, acc.z);
                acc.w = fmaf(v, r.w, acc.w);
            }
        }
    }
    acc.x += __shfl_xor(acc.x, 16);
    acc.y += __shfl_xor(acc.y, 16);
    acc.z += __shfl_xor(acc.z, 16);
    acc.w += __shfl_xor(acc.w, 16);
    acc.x += __shfl_xor(acc.x, 32);
    acc.y += __shfl_xor(acc.y, 32);
    acc.z += __shfl_xor(acc.z, 32);
    acc.w += __shfl_xor(acc.w, 32);
    if (lane < 16)
        ((float4*)(xout + (size_t)node * DIM))[d4] = acc;
}

__global__ __launch_bounds__(256) void spmm_selP_kernel(const int2* __restrict__ packed,
                                                        const int* __restrict__ deg,
                                                        const int* __restrict__ users,
                                                        const int* __restrict__ items,
                                                        const float* __restrict__ h2,
                                                        float* __restrict__ acc_sel) {
    int gtid = blockIdx.x * blockDim.x + threadIdx.x;
    int slot = gtid >> 6;
    int lane = threadIdx.x & 63;
    if (slot >= 2 * BATCH_C) return;
    int node = (slot < BATCH_C) ? users[slot] : (NUM_USERS + items[slot - BATCH_C]);
    int nd = deg[node];
    if (nd > CAP) nd = CAP;
    const int2* row = packed + (size_t)node * CAP;
    int q  = lane >> 4;
    int d4 = lane & 15;
    const float4* xbase = (const float4*)h2 + d4;
    float4 acc = make_float4(0.f, 0.f, 0.f, 0.f);

    for (int base = 0; base < nd; base += 64) {
        int n = nd - base;
        n = n > 64 ? 64 : n;
        int2 p = make_int2(0, 0);
        if (lane < n) p = row[base + lane];
        int nq = (n + 3) >> 2;
        #pragma unroll 4
        for (int t = 0; t < nq; ++t) {
            int srclane = (4 * t + q) << 2;
            int s  = __builtin_amdgcn_ds_bpermute(srclane, p.x);
            float v = __int_as_float(__builtin_amdgcn_ds_bpermute(srclane, p.y));
            float4 r = xbase[s * 16];
            acc.x = fmaf(v, r.x, acc.x);
            acc.y = fmaf(v, r.y, acc.y);
            acc.z = fmaf(v, r.z, acc.z);
            acc.w = fmaf(v, r.w, acc.w);
        }
    }
    acc.x += __shfl_xor(acc.x, 16);
    acc.y += __shfl_xor(acc.y, 16);
    acc.z += __shfl_xor(acc.z, 16);
    acc.w += __shfl_xor(acc.w, 16);
    acc.x += __shfl_xor(acc.x, 32);
    acc.y += __shfl_xor(acc.y, 32);
    acc.z += __shfl_xor(acc.z, 32);
    acc.w += __shfl_xor(acc.w, 32);
    if (lane < 16) {
        float4* dst4 = (float4*)(acc_sel + (size_t)slot * DIM) + d4;
        float4 a = *dst4;
        a.x += acc.x; a.y += acc.y; a.z += acc.z; a.w += acc.w;
        *dst4 = a;
    }
}

// ================= FALLBACK path (round-10 measured: CSR via count+scan) ===

__global__ __launch_bounds__(256) void count_kernel(const int4* __restrict__ dst4,
                                                    int* __restrict__ cnt) {
    int i = blockIdx.x * blockDim.x + threadIdx.x;
    int stride = gridDim.x * blockDim.x;
    const int N4 = NNZ_C / 4;
    for (; i < N4; i += stride) {
        int4 d = dst4[i];
        atomicAdd(&cnt[d.x], 1);
        atomicAdd(&cnt[d.y], 1);
        atomicAdd(&cnt[d.z], 1);
        atomicAdd(&cnt[d.w], 1);
    }
}

__global__ __launch_bounds__(256) void scanA_kernel(const int* __restrict__ cnt,
                                                    int* __restrict__ row_ptr,
                                                    int* __restrict__ chunk_sums) {
    __shared__ int sh[256];
    int b = blockIdx.x, t = threadIdx.x;
    int base = b * 1024 + t * 4;
    int v0 = (base + 0 < N_NODES) ? cnt[base + 0] : 0;
    int v1 = (base + 1 < N_NODES) ? cnt[base + 1] : 0;
    int v2 = (base + 2 < N_NODES) ? cnt[base + 2] : 0;
    int v3 = (base + 3 < N_NODES) ? cnt[base + 3] : 0;
    int s = v0 + v1 + v2 + v3;
    sh[t] = s;
    __syncthreads();
    for (int off = 1; off < 256; off <<= 1) {
        int x = (t >= off) ? sh[t - off] : 0;
        __syncthreads();
        sh[t] += x;
        __syncthreads();
    }
    int excl = sh[t] - s;
    if (t == 255) chunk_sums[b] = sh[255];
    int run = excl;
    if (base + 0 < N_NODES) { row_ptr[base + 0] = run; run += v0; }
    if (base + 1 < N_NODES) { row_ptr[base + 1] = run; run += v1; }
    if (base + 2 < N_NODES) { row_ptr[base + 2] = run; run += v2; }
    if (base + 3 < N_NODES) { row_ptr[base + 3] = run; run += v3; }
}

__global__ void scanB_kernel(int* __restrict__ chunk_sums) {
    if (threadIdx.x == 0 && blockIdx.x == 0) {
        int run = 0;
        for (int i = 0; i < NCHUNKS; ++i) {
            int c = chunk_sums[i];
            chunk_sums[i] = run;
            run += c;
        }
    }
}

__global__ __launch_bounds__(256) void scanC_kernel(int* __restrict__ row_ptr,
                                                    int* __restrict__ cursor,
                                                    const int* __restrict__ chunk_offs) {
    int i = blockIdx.x * blockDim.x + threadIdx.x;
    if (i < N_NODES) {
        int v = row_ptr[i] + chunk_offs[i >> 10];
        row_ptr[i] = v;
        cursor[i] = v;
    } else if (i == N_NODES) {
        row_ptr[i] = NNZ_C;
    }
}

__global__ __launch_bounds__(256) void scatter_kernel(const int* __restrict__ src,
                                                      const int* __restrict__ dst,
                                                      const float* __restrict__ val,
                                                      int2* __restrict__ packed,
                                                      int* __restrict__ cursor) {
    int i = blockIdx.x * blockDim.x + threadIdx.x;
    int stride = gridDim.x * blockDim.x;
    for (; i < NNZ_C; i += stride) {
        int d = dst[i];
        int p = atomicAdd(&cursor[d], 1);
        packed[p] = make_int2(src[i], __float_as_int(val[i]));
    }
}

__global__ __launch_bounds__(256) void spmm_kernel(const int2* __restrict__ packed,
                                                   const int* __restrict__ row_ptr,
                                                   const float* __restrict__ xin,
                                                   float* __restrict__ xout) {
    int gtid = blockIdx.x * blockDim.x + threadIdx.x;
    int node = gtid >> 6;
    int lane = threadIdx.x & 63;
    if (node >= N_NODES) return;
    int beg = row_ptr[node];
    int end = row_ptr[node + 1];
    int q  = lane >> 4;
    int d4 = lane & 15;
    const float4* xbase = (const float4*)xin + d4;
    float4 acc = make_float4(0.f, 0.f, 0.f, 0.f);

    for (int base = beg; base < end; base += 64) {
        int n = end - base;
        n = n > 64 ? 64 : n;
        int2 p = make_int2(0, 0);
        if (lane < n) p = packed[base + lane];
        if (n == 64) {
            #pragma unroll
            for (int t = 0; t < 16; ++t) {
                int srclane = (4 * t + q) << 2;
                int s  = __builtin_amdgcn_ds_bpermute(srclane, p.x);
                float v = __int_as_float(__builtin_amdgcn_ds_bpermute(srclane, p.y));
                float4 r = xbase[s * 16];
                acc.x = fmaf(v, r.x, acc.x);
                acc.y = fmaf(v, r.y, acc.y);
                acc.z = fmaf(v, r.z, acc.z);
                acc.w = fmaf(v, r.w, acc.w);
            }
        } else {
            int nq = (n + 3) >> 2;
            #pragma unroll 4
            for (int t = 0; t < nq; ++t) {
                int srclane = (4 * t + q) << 2;
                int s  = __builtin_amdgcn_ds_bpermute(srclane, p.x);
                float v = __int_as_float(__builtin_amdgcn_ds_bpermute(srclane, p.y));
                float4 r = xbase[s * 16];
                acc.x = fmaf(v, r.x, acc.x);
                acc.y = fmaf(v, r.y, acc.y);
                acc.z = fmaf(v, r.z, acc.z);
                acc.w = fmaf(v, r.w, acc.w);
            }
        }
    }
    acc.x += __shfl_xor(acc.x, 16);
    acc.y += __shfl_xor(acc.y, 16);
    acc.z += __shfl_xor(acc.z, 16);
    acc.w += __shfl_xor(acc.w, 16);
    acc.x += __shfl_xor(acc.x, 32);
    acc.y += __shfl_xor(acc.y, 32);
    acc.z += __shfl_xor(acc.z, 32);
    acc.w += __shfl_xor(acc.w, 32);
    if (lane < 16)
        ((float4*)(xout + (size_t)node * DIM))[d4] = acc;
}

__global__ __launch_bounds__(256) void spmm_sel_kernel(const int2* __restrict__ packed,
                                                       const int* __restrict__ row_ptr,
                                                       const int* __restrict__ users,
                                                       const int* __restrict__ items,
                                                       const float* __restrict__ h2,
                                                       float* __restrict__ acc_sel) {
    int gtid = blockIdx.x * blockDim.x + threadIdx.x;
    int slot = gtid >> 6;
    int lane = threadIdx.x & 63;
    if (slot >= 2 * BATCH_C) return;
    int node = (slot < BATCH_C) ? users[slot] : (NUM_USERS + items[slot - BATCH_C]);
    int beg = row_ptr[node];
    int end = row_ptr[node + 1];
    int q  = lane >> 4;
    int d4 = lane & 15;
    const float4* xbase = (const float4*)h2 + d4;
    float4 acc = make_float4(0.f, 0.f, 0.f, 0.f);

    for (int base = beg; base < end; base += 64) {
        int n = end - base;
        n = n > 64 ? 64 : n;
        int2 p = make_int2(0, 0);
        if (lane < n) p = packed[base + lane];
        int nq = (n + 3) >> 2;
        #pragma unroll 4
        for (int t = 0; t < nq; ++t) {
            int srclane = (4 * t + q) << 2;
            int s  = __builtin_amdgcn_ds_bpermute(srclane, p.x);
            float v = __int_as_float(__builtin_amdgcn_ds_bpermute(srclane, p.y));
            float4 r = xbase[s * 16];
            acc.x = fmaf(v, r.x, acc.x);
            acc.y = fmaf(v, r.y, acc.y);
            acc.z = fmaf(v, r.z, acc.z);
            acc.w = fmaf(v, r.w, acc.w);
        }
    }
    acc.x += __shfl_xor(acc.x, 16);
    acc.y += __shfl_xor(acc.y, 16);
    acc.z += __shfl_xor(acc.z, 16);
    acc.w += __shfl_xor(acc.w, 16);
    acc.x += __shfl_xor(acc.x, 32);
    acc.y += __shfl_xor(acc.y, 32);
    acc.z += __shfl_xor(acc.z, 32);
    acc.w += __shfl_xor(acc.w, 32);
    if (lane < 16) {
        float4* dst4 = (float4*)(acc_sel + (size_t)slot * DIM) + d4;
        float4 a = *dst4;
        a.x += acc.x; a.y += acc.y; a.z += acc.z; a.w += acc.w;
        *dst4 = a;
    }
}

// ---------------- launch ----------------

extern "C" void kernel_launch(void* const* d_in, const int* in_sizes, int n_in,
                              void* d_out, int out_size, void* d_ws, size_t ws_size,
                              hipStream_t stream) {
    const int*   users = (const int*)d_in[0];
    const int*   items = (const int*)d_in[1];
    const float* uemb  = (const float*)d_in[2];
    const float* iemb  = (const float*)d_in[3];
    const int*   esrc  = (const int*)d_in[4];
    const int*   edst  = (const int*)d_in[5];
    const float* eval  = (const float*)d_in[6];
    float*       out   = (float*)d_out;

    char* ws = (char*)d_ws;

    // padded layout needs: 150000*128*8 + 2*38,400,000 + 2,097,152 + 600,000
    const size_t PAD_NEEDED = 153600000ull + 38400000ull + 38400000ull
                            + 2097152ull + 600000ull;   // = 233,097,152

    if (ws_size >= PAD_NEEDED) {
        // ---------- padded-bucket path: no count, no scan ----------
        int2*  packed  = (int2*)(ws + 0);              // 153,600,000
        float* X       = (float*)(ws + 153600000);     //  38,400,000
        float* hA      = (float*)(ws + 192000000);     //  38,400,000
        float* acc_sel = (float*)(ws + 230400000);     //   2,097,152
        int*   deg     = (int*)(ws + 232497152);       //     600,000

        hipMemsetAsync(deg, 0, N_NODES * sizeof(int), stream);
        scatterP_kernel<<<2048, 256, 0, stream>>>(esrc, edst, eval, packed, deg);

        concat_kernel<<<2048, 256, 0, stream>>>(uemb, iemb, (float4*)X);
        init_sel_kernel<<<(2 * BATCH_C * 16 + 255) / 256, 256, 0, stream>>>(users, items, X, acc_sel);

        const int spmm_blocks = N_NODES / 4;
        spmmP_kernel<<<spmm_blocks, 256, 0, stream>>>(packed, deg, X, hA);
        add_sel_kernel<<<(2 * BATCH_C * 16 + 255) / 256, 256, 0, stream>>>(users, items, hA, acc_sel);
        spmmP_kernel<<<spmm_blocks, 256, 0, stream>>>(packed, deg, hA, X);
        add_sel_kernel<<<(2 * BATCH_C * 16 + 255) / 256, 256, 0, stream>>>(users, items, X, acc_sel);
        spmm_selP_kernel<<<(2 * BATCH_C) / 4, 256, 0, stream>>>(packed, deg, users, items, X, acc_sel);

        dot_kernel<<<BATCH_C / 4, 256, 0, stream>>>(acc_sel, out);
    } else {
        // ---------- fallback: exact round-10 measured path ----------
        int2*  packed   = (int2*)(ws + 0);             // 80,000,000
        float* X        = (float*)(ws + 80000000);     // 38,400,000
        float* hA       = (float*)(ws + 118400000);    // 38,400,000
        float* acc_sel  = (float*)(ws + 156800000);    // 2,097,152
        int*   row_ptr  = (int*)(ws + 158897152);      // 600,004
        int*   cursor   = (int*)(ws + 159497168);      // 600,000
        int*   chunk_s  = (int*)(ws + 160097168);      // 1,024

        hipMemsetAsync(cursor, 0, N_NODES * sizeof(int), stream);
        count_kernel<<<2048, 256, 0, stream>>>((const int4*)edst, cursor);
        scanA_kernel<<<NCHUNKS, 256, 0, stream>>>(cursor, row_ptr, chunk_s);
        scanB_kernel<<<1, 64, 0, stream>>>(chunk_s);
        scanC_kernel<<<(N_NODES + 256) / 256, 256, 0, stream>>>(row_ptr, cursor, chunk_s);
        scatter_kernel<<<2048, 256, 0, stream>>>(esrc, edst, eval, packed, cursor);

        concat_kernel<<<2048, 256, 0, stream>>>(uemb, iemb, (float4*)X);
        init_sel_kernel<<<(2 * BATCH_C * 16 + 255) / 256, 256, 0, stream>>>(users, items, X, acc_sel);

        const int spmm_blocks = N_NODES / 4;
        spmm_kernel<<<spmm_blocks, 256, 0, stream>>>(packed, row_ptr, X, hA);
        add_sel_kernel<<<(2 * BATCH_C * 16 + 255) / 256, 256, 0, stream>>>(users, items, hA, acc_sel);
        spmm_kernel<<<spmm_blocks, 256, 0, stream>>>(packed, row_ptr, hA, X);
        add_sel_kernel<<<(2 * BATCH_C * 16 + 255) / 256, 256, 0, stream>>>(users, items, X, acc_sel);
        spmm_sel_kernel<<<(2 * BATCH_C) / 4, 256, 0, stream>>>(packed, row_ptr, users, items, X, acc_sel);

        dot_kernel<<<BATCH_C / 4, 256, 0, stream>>>(acc_sel, out);
    }
}

// Round 12
// 1143.663 us; speedup vs baseline: 1.9987x; 1.1671x over previous
//
#include <hip/hip_runtime.h>

#define NUM_USERS 100000
#define NUM_ITEMS 50000
#define N_NODES   150000   // NUM_USERS + NUM_ITEMS
#define DIM       64
#define NNZ_C     10000000
#define BATCH_C   4096
#define NBINS     1172     // ceil(150000/128); bin = dst >> 7 (128 nodes/bin)
#define NBLK      2048
#define CHUNK     4883     // ceil(NNZ / NBLK); 2048*4883 = 10,000,384

// ======== Phase A: per-block histogram over bins (LDS atomics only) ========

__global__ __launch_bounds__(256) void histA_kernel(const int* __restrict__ dst,
                                                    int* __restrict__ H) {
    __shared__ int hist[NBINS];
    int bid = blockIdx.x, t = threadIdx.x;
    for (int i = t; i < NBINS; i += 256) hist[i] = 0;
    __syncthreads();
    int beg = bid * CHUNK;
    int end = beg + CHUNK; if (end > NNZ_C) end = NNZ_C;
    for (int i = beg + t; i < end; i += 256) atomicAdd(&hist[dst[i] >> 7], 1);
    __syncthreads();
    for (int i = t; i < NBINS; i += 256) H[bid * NBINS + i] = hist[i];
}

// ======== Phase B1: per-bin exclusive scan over blocks (H -> O_rel) ========

__global__ __launch_bounds__(256) void scanB1_kernel(int* __restrict__ H,
                                                     int* __restrict__ bin_cnt) {
    __shared__ int sh[256];
    int b = blockIdx.x;       // bin
    int t = threadIdx.x;      // covers blocks [t*8, t*8+8)
    int v[8]; int s = 0;
    #pragma unroll
    for (int j = 0; j < 8; ++j) { v[j] = H[(t * 8 + j) * NBINS + b]; s += v[j]; }
    sh[t] = s;
    __syncthreads();
    for (int off = 1; off < 256; off <<= 1) {
        int x = (t >= off) ? sh[t - off] : 0;
        __syncthreads();
        sh[t] += x;
        __syncthreads();
    }
    int run = sh[t] - s;
    if (t == 255) bin_cnt[b] = sh[255];
    #pragma unroll
    for (int j = 0; j < 8; ++j) { H[(t * 8 + j) * NBINS + b] = run; run += v[j]; }
}

// ======== Phase B2: exclusive scan of bin counts -> bin_start ========

__global__ void scanB2_kernel(const int* __restrict__ bin_cnt,
                              int* __restrict__ bin_start,
                              int* __restrict__ row_ptr) {
    __shared__ int sh[256];
    int t = threadIdx.x;
    int v[5]; int s = 0;
    #pragma unroll
    for (int j = 0; j < 5; ++j) {
        int idx = t * 5 + j;
        v[j] = (idx < NBINS) ? bin_cnt[idx] : 0;
        s += v[j];
    }
    sh[t] = s;
    __syncthreads();
    for (int off = 1; off < 256; off <<= 1) {
        int x = (t >= off) ? sh[t - off] : 0;
        __syncthreads();
        sh[t] += x;
        __syncthreads();
    }
    int run = sh[t] - s;
    #pragma unroll
    for (int j = 0; j < 5; ++j) {
        int idx = t * 5 + j;
        if (idx < NBINS) bin_start[idx] = run;
        run += v[j];
    }
    if (t == 0) { bin_start[NBINS] = NNZ_C; row_ptr[N_NODES] = NNZ_C; }
}

// ======== Phase C: LDS counting-sort by bin, stream to bin-contiguous buf ===
// edge packed 8B: hi = src | (local_dst<<18)  (src<2^18, local_dst<128), lo = val bits

__global__ __launch_bounds__(256) void partC_kernel(const int* __restrict__ src,
                                                    const int* __restrict__ dst,
                                                    const float* __restrict__ val,
                                                    const int* __restrict__ H,   // O_rel
                                                    const int* __restrict__ bin_start,
                                                    int2* __restrict__ binBuf) {
    __shared__ int2  edg[CHUNK];     // 39,064 B
    __shared__ short ebin[CHUNK];    //  9,766 B
    __shared__ int   hist[NBINS];    //  4,688 B (later: cursor)
    __shared__ int   lscan[NBINS];   //  4,688 B
    __shared__ int   sh2[256];       //  1,024 B   (total ~59.2 KB)
    int bid = blockIdx.x, t = threadIdx.x;
    int beg = bid * CHUNK;
    int end = beg + CHUNK; if (end > NNZ_C) end = NNZ_C;
    int cnt = end - beg;

    for (int i = t; i < NBINS; i += 256) hist[i] = 0;
    __syncthreads();
    for (int i = beg + t; i < end; i += 256) atomicAdd(&hist[dst[i] >> 7], 1);
    __syncthreads();

    // exclusive scan hist -> lscan (segmented: 5 elems/thread)
    int v[5]; int s = 0;
    #pragma unroll
    for (int j = 0; j < 5; ++j) {
        int idx = t * 5 + j;
        v[j] = (idx < NBINS) ? hist[idx] : 0;
        s += v[j];
    }
    sh2[t] = s;
    __syncthreads();
    for (int off = 1; off < 256; off <<= 1) {
        int x = (t >= off) ? sh2[t - off] : 0;
        __syncthreads();
        sh2[t] += x;
        __syncthreads();
    }
    int run = sh2[t] - s;
    #pragma unroll
    for (int j = 0; j < 5; ++j) {
        int idx = t * 5 + j;
        if (idx < NBINS) lscan[idx] = run;
        run += v[j];
    }
    __syncthreads();
    for (int i = t; i < NBINS; i += 256) hist[i] = 0;   // reset as cursor
    __syncthreads();

    // LDS scatter into bin-sorted order
    for (int i = beg + t; i < end; i += 256) {
        int d = dst[i];
        int b = d >> 7, ld = d & 127;
        int pos = lscan[b] + atomicAdd(&hist[b], 1);
        edg[pos]  = make_int2(src[i] | (ld << 18), __float_as_int(val[i]));
        ebin[pos] = (short)b;
    }
    __syncthreads();

    // stream out: ascending bins -> mostly-coalesced, block-private runs
    for (int i = t; i < cnt; i += 256) {
        int b = ebin[i];
        int addr = bin_start[b] + H[bid * NBINS + b] + (i - lscan[b]);
        binBuf[addr] = edg[i];
    }
}

// ======== Phase D: per-bin CSR finalize (one workgroup per bin) ========

__global__ __launch_bounds__(256) void finD_kernel(const int2* __restrict__ binBuf,
                                                   const int* __restrict__ bin_start,
                                                   int2* __restrict__ packed,
                                                   int* __restrict__ row_ptr) {
    __shared__ int hist[128], lscan[128], cur[128];
    int b = blockIdx.x, t = threadIdx.x;
    int beg = bin_start[b], end = bin_start[b + 1];
    if (t < 128) hist[t] = 0;
    __syncthreads();
    for (int i = beg + t; i < end; i += 256)
        atomicAdd(&hist[(binBuf[i].x >> 18) & 127], 1);
    __syncthreads();
    int sv = (t < 128) ? hist[t] : 0;
    if (t < 128) lscan[t] = sv;
    __syncthreads();
    for (int off = 1; off < 128; off <<= 1) {
        int x = 0;
        if (t < 128 && t >= off) x = lscan[t - off];
        __syncthreads();
        if (t < 128) lscan[t] += x;
        __syncthreads();
    }
    if (t < 128) {
        lscan[t] -= sv;           // exclusive
        cur[t] = 0;
        int node = b * 128 + t;
        if (node < N_NODES) row_ptr[node] = beg + lscan[t];
    }
    __syncthreads();
    for (int i = beg + t; i < end; i += 256) {
        int2 e = binBuf[i];
        int ld = (e.x >> 18) & 127;
        int slot = beg + lscan[ld] + atomicAdd(&cur[ld], 1);
        packed[slot] = make_int2(e.x & 0x3FFFF, e.y);
    }
}

// ======== X = concat(uemb, iemb) ========

__global__ __launch_bounds__(256) void concat_kernel(const float* __restrict__ uemb,
                                                     const float* __restrict__ iemb,
                                                     float4* __restrict__ X4) {
    const int NU4 = NUM_USERS * DIM / 4;
    const int NT4 = N_NODES * DIM / 4;
    int i = blockIdx.x * blockDim.x + threadIdx.x;
    int stride = gridDim.x * blockDim.x;
    const float4* u4 = (const float4*)uemb;
    const float4* i4 = (const float4*)iemb;
    for (; i < NT4; i += stride)
        X4[i] = (i < NU4) ? u4[i] : i4[i - NU4];
}

// ======== SpMM (measured round-10 CSR form) ========

__global__ __launch_bounds__(256) void spmm_kernel(const int2* __restrict__ packed,
                                                   const int* __restrict__ row_ptr,
                                                   const float* __restrict__ xin,
                                                   float* __restrict__ xout) {
    int gtid = blockIdx.x * blockDim.x + threadIdx.x;
    int node = gtid >> 6;
    int lane = threadIdx.x & 63;
    if (node >= N_NODES) return;
    int beg = row_ptr[node];
    int end = row_ptr[node + 1];
    int q  = lane >> 4;
    int d4 = lane & 15;
    const float4* xbase = (const float4*)xin + d4;
    float4 acc = make_float4(0.f, 0.f, 0.f, 0.f);

    for (int base = beg; base < end; base += 64) {
        int n = end - base;
        n = n > 64 ? 64 : n;
        int2 p = make_int2(0, 0);
        if (lane < n) p = packed[base + lane];
        if (n == 64) {
            #pragma unroll
            for (int t = 0; t < 16; ++t) {
                int srclane = (4 * t + q) << 2;
                int s  = __builtin_amdgcn_ds_bpermute(srclane, p.x);
                float v = __int_as_float(__builtin_amdgcn_ds_bpermute(srclane, p.y));
                float4 r = xbase[s * 16];
                acc.x = fmaf(v, r.x, acc.x);
                acc.y = fmaf(v, r.y, acc.y);
                acc.z = fmaf(v, r.z, acc.z);
                acc.w = fmaf(v, r.w, acc.w);
            }
        } else {
            int nq = (n + 3) >> 2;
            #pragma unroll 4
            for (int t = 0; t < nq; ++t) {
                int srclane = (4 * t + q) << 2;
                int s  = __builtin_amdgcn_ds_bpermute(srclane, p.x);
                float v = __int_as_float(__builtin_amdgcn_ds_bpermute(srclane, p.y));
                float4 r = xbase[s * 16];
                acc.x = fmaf(v, r.x, acc.x);
                acc.y = fmaf(v, r.y, acc.y);
                acc.z = fmaf(v, r.z, acc.z);
                acc.w = fmaf(v, r.w, acc.w);
            }
        }
    }
    acc.x += __shfl_xor(acc.x, 16);
    acc.y += __shfl_xor(acc.y, 16);
    acc.z += __shfl_xor(acc.z, 16);
    acc.w += __shfl_xor(acc.w, 16);
    acc.x += __shfl_xor(acc.x, 32);
    acc.y += __shfl_xor(acc.y, 32);
    acc.z += __shfl_xor(acc.z, 32);
    acc.w += __shfl_xor(acc.w, 32);
    if (lane < 16)
        ((float4*)(xout + (size_t)node * DIM))[d4] = acc;
}

__global__ __launch_bounds__(256) void spmm_sel_kernel(const int2* __restrict__ packed,
                                                       const int* __restrict__ row_ptr,
                                                       const int* __restrict__ users,
                                                       const int* __restrict__ items,
                                                       const float* __restrict__ h2,
                                                       float* __restrict__ acc_sel) {
    int gtid = blockIdx.x * blockDim.x + threadIdx.x;
    int slot = gtid >> 6;
    int lane = threadIdx.x & 63;
    if (slot >= 2 * BATCH_C) return;
    int node = (slot < BATCH_C) ? users[slot] : (NUM_USERS + items[slot - BATCH_C]);
    int beg = row_ptr[node];
    int end = row_ptr[node + 1];
    int q  = lane >> 4;
    int d4 = lane & 15;
    const float4* xbase = (const float4*)h2 + d4;
    float4 acc = make_float4(0.f, 0.f, 0.f, 0.f);

    for (int base = beg; base < end; base += 64) {
        int n = end - base;
        n = n > 64 ? 64 : n;
        int2 p = make_int2(0, 0);
        if (lane < n) p = packed[base + lane];
        int nq = (n + 3) >> 2;
        #pragma unroll 4
        for (int t = 0; t < nq; ++t) {
            int srclane = (4 * t + q) << 2;
            int s  = __builtin_amdgcn_ds_bpermute(srclane, p.x);
            float v = __int_as_float(__builtin_amdgcn_ds_bpermute(srclane, p.y));
            float4 r = xbase[s * 16];
            acc.x = fmaf(v, r.x, acc.x);
            acc.y = fmaf(v, r.y, acc.y);
            acc.z = fmaf(v, r.z, acc.z);
            acc.w = fmaf(v, r.w, acc.w);
        }
    }
    acc.x += __shfl_xor(acc.x, 16);
    acc.y += __shfl_xor(acc.y, 16);
    acc.z += __shfl_xor(acc.z, 16);
    acc.w += __shfl_xor(acc.w, 16);
    acc.x += __shfl_xor(acc.x, 32);
    acc.y += __shfl_xor(acc.y, 32);
    acc.z += __shfl_xor(acc.z, 32);
    acc.w += __shfl_xor(acc.w, 32);
    if (lane < 16) {
        float4* dst4 = (float4*)(acc_sel + (size_t)slot * DIM) + d4;
        float4 a = *dst4;
        a.x += acc.x; a.y += acc.y; a.z += acc.z; a.w += acc.w;
        *dst4 = a;
    }
}

// ======== selected-row accumulation + dot ========

__global__ __launch_bounds__(256) void init_sel_kernel(const int* __restrict__ users,
                                                       const int* __restrict__ items,
                                                       const float* __restrict__ X,
                                                       float* __restrict__ acc_sel) {
    int gtid = blockIdx.x * blockDim.x + threadIdx.x;
    int idx = gtid >> 4;
    int l = threadIdx.x & 15;
    if (idx >= 2 * BATCH_C) return;
    int node = (idx < BATCH_C) ? users[idx] : (NUM_USERS + items[idx - BATCH_C]);
    ((float4*)(acc_sel + (size_t)idx * DIM))[l] =
        ((const float4*)(X + (size_t)node * DIM))[l];
}

__global__ __launch_bounds__(256) void add_sel_kernel(const int* __restrict__ users,
                                                      const int* __restrict__ items,
                                                      const float* __restrict__ h,
                                                      float* __restrict__ acc_sel) {
    int gtid = blockIdx.x * blockDim.x + threadIdx.x;
    int idx = gtid >> 4;
    int l = threadIdx.x & 15;
    if (idx >= 2 * BATCH_C) return;
    int node = (idx < BATCH_C) ? users[idx] : (NUM_USERS + items[idx - BATCH_C]);
    float4 a = ((float4*)(acc_sel + (size_t)idx * DIM))[l];
    float4 b = ((const float4*)(h + (size_t)node * DIM))[l];
    a.x += b.x; a.y += b.y; a.z += b.z; a.w += b.w;
    ((float4*)(acc_sel + (size_t)idx * DIM))[l] = a;
}

__global__ __launch_bounds__(256) void dot_kernel(const float* __restrict__ acc_sel,
                                                  float* __restrict__ out) {
    int gtid = blockIdx.x * blockDim.x + threadIdx.x;
    int b = gtid >> 6;
    int lane = threadIdx.x & 63;
    if (b >= BATCH_C) return;
    float u = acc_sel[(size_t)b * DIM + lane];
    float v = acc_sel[(size_t)(BATCH_C + b) * DIM + lane];
    float p = u * v;
    for (int off = 32; off > 0; off >>= 1) p += __shfl_xor(p, off);
    if (lane == 0) out[b] = p * 0.0625f;  // (1/4)^2 for the two light_out rows
}

// ======== launch ========

extern "C" void kernel_launch(void* const* d_in, const int* in_sizes, int n_in,
                              void* d_out, int out_size, void* d_ws, size_t ws_size,
                              hipStream_t stream) {
    const int*   users = (const int*)d_in[0];
    const int*   items = (const int*)d_in[1];
    const float* uemb  = (const float*)d_in[2];
    const float* iemb  = (const float*)d_in[3];
    const int*   esrc  = (const int*)d_in[4];
    const int*   edst  = (const int*)d_in[5];
    const float* eval  = (const float*)d_in[6];
    float*       out   = (float*)d_out;

    char* ws = (char*)d_ws;
    // layout (~172.3 MB; ws >= 233 MB established by round 11):
    int2*  packed    = (int2*)(ws + 0);              // 80,000,000 (exact CSR)
    int2*  binBuf    = (int2*)(ws + 80000000);       // 80,000,000 (dead after finD)
    float* X         = (float*)(ws + 80000000);      // 38,400,000 (overlays binBuf)
    float* hA        = (float*)(ws + 118400000);     // 38,400,000 (overlays binBuf)
    int*   H         = (int*)(ws + 160000000);       //  9,601,024 (NBLK x NBINS)
    int*   bin_cnt   = (int*)(ws + 169601024);       //      4,688
    int*   bin_start = (int*)(ws + 169605712);       //      4,692
    int*   row_ptr   = (int*)(ws + 169610404);       //    600,004
    float* acc_sel   = (float*)(ws + 170210416);     //  2,097,152

    // 1) atomic-free CSR build: hist -> scan -> partition -> finalize
    histA_kernel<<<NBLK, 256, 0, stream>>>(edst, H);
    scanB1_kernel<<<NBINS, 256, 0, stream>>>(H, bin_cnt);
    scanB2_kernel<<<1, 256, 0, stream>>>(bin_cnt, bin_start, row_ptr);
    partC_kernel<<<NBLK, 256, 0, stream>>>(esrc, edst, eval, H, bin_start, binBuf);
    finD_kernel<<<NBINS, 256, 0, stream>>>(binBuf, bin_start, packed, row_ptr);

    // 2) X = concat (overlays binBuf AFTER finD); selected-row init
    concat_kernel<<<2048, 256, 0, stream>>>(uemb, iemb, (float4*)X);
    init_sel_kernel<<<(2 * BATCH_C * 16 + 255) / 256, 256, 0, stream>>>(users, items, X, acc_sel);

    // 3) layers 1,2 full; layer 3 restricted to batch
    const int spmm_blocks = N_NODES / 4;
    spmm_kernel<<<spmm_blocks, 256, 0, stream>>>(packed, row_ptr, X, hA);
    add_sel_kernel<<<(2 * BATCH_C * 16 + 255) / 256, 256, 0, stream>>>(users, items, hA, acc_sel);
    spmm_kernel<<<spmm_blocks, 256, 0, stream>>>(packed, row_ptr, hA, X);
    add_sel_kernel<<<(2 * BATCH_C * 16 + 255) / 256, 256, 0, stream>>>(users, items, X, acc_sel);
    spmm_sel_kernel<<<(2 * BATCH_C) / 4, 256, 0, stream>>>(packed, row_ptr, users, items, X, acc_sel);

    // 4) final dot products
    dot_kernel<<<BATCH_C / 4, 256, 0, stream>>>(acc_sel, out);
}